// Round 2
// baseline (7843.957 us; speedup 1.0000x reference)
//
#include <hip/hip_runtime.h>
#include <stdint.h>

#define Hd 768
#define H3 2304
#define Bsz 64
#define Lseq 512
#define MROWS 32768           // L*B real rows
#define MPAD 32896            // 257*128
#define NB 8                  // batch per cluster
#define NCLUST 8
#define CUS_PER 12

// ---- workspace layout (bytes) ----
#define OFF_W   50528256UL          // after X (MPAD*768*2)
#define W_SZ    9451072UL
#define OFF_GI  (OFF_W + W_SZ)      // 59,979,328
#define SZ_GI_F 303169536UL
#define SZ_GI_H 151584768UL
#define SZ_H    393216UL
#define SZ_FIN  196608UL
// converted-region element offsets (ushort index from ws+OFF_W)
#define E_WIH 0UL
#define E_WHH 1769472UL
#define E_BIH 3538944UL
#define E_BHH 3541248UL
#define E_SW0 3543552UL
#define E_SB0 4133376UL
#define E_SW1 4134144UL
#define E_SB1 4723968UL
#define E_SWO 4724736UL
#define E_SBO 4725504UL
#define E_TOT 4725505UL

typedef float v4f __attribute__((ext_vector_type(4)));
typedef short short8 __attribute__((ext_vector_type(8)));

__device__ inline float bf2f(unsigned short u){
  union { unsigned int i; float f; } v; v.i = ((unsigned int)u) << 16; return v.f;
}
__device__ inline unsigned short f2bf(float f){
  union { float f; unsigned int i; } v; v.f = f;
  unsigned int x = v.i;
  return (unsigned short)((x + 0x7fffu + ((x >> 16) & 1u)) >> 16);
}
__device__ inline float sigmoidf_(float x){ return 1.f/(1.f + __expf(-x)); }
__device__ inline float tanhf_(float x){
  float a = fabsf(x);
  float e = __expf(-2.f*a);
  float t = (1.f - e)/(1.f + e);
  return copysignf(t, x);
}

// ---------------- kZ: zero control/accumulator region ----------------
__global__ void kZ(uint4* p, int n16){
  int idx = blockIdx.x*blockDim.x + threadIdx.x;
  uint4 z; z.x=0; z.y=0; z.z=0; z.w=0;
  for (int i = idx; i < n16; i += gridDim.x*blockDim.x) p[i] = z;
}

// ---------------- kDet: detect fp32 (1) vs bf16 (0) input encoding ----------
__global__ void kDet(const unsigned short* __restrict__ emb_u, unsigned int* flag){
  __shared__ int cnt;
  if (threadIdx.x == 0) cnt = 0;
  __syncthreads();
  int local = 0;
  for (int i = threadIdx.x; i < 4096; i += 256){
    unsigned short b = emb_u[2*i];          // low half if fp32-underneath
    int e = (b >> 7) & 0xFF;
    if (e >= 0x89) local++;                 // |bf16| >= 2^10 (or NaN/inf)
  }
  atomicAdd(&cnt, local);
  __syncthreads();
  if (threadIdx.x == 0) *flag = (cnt > 64) ? 1u : 0u;
}

// ---------------- kCvt: weights -> bf16 copies in ws ----------------
struct CvtArgs { const void* s[10]; };
__global__ __launch_bounds__(256) void kCvt(CvtArgs a, unsigned short* __restrict__ dst,
                                            const unsigned int* __restrict__ flag){
  size_t e = (size_t)blockIdx.x*256 + threadIdx.x;
  if (e >= E_TOT) return;
  int fp32 = (int)*flag;
  int s; size_t base;
  if      (e < E_WHH) { s=0; base=E_WIH; }
  else if (e < E_BIH) { s=1; base=E_WHH; }
  else if (e < E_BHH) { s=2; base=E_BIH; }
  else if (e < E_SW0) { s=3; base=E_BHH; }
  else if (e < E_SB0) { s=4; base=E_SW0; }
  else if (e < E_SW1) { s=5; base=E_SB0; }
  else if (e < E_SB1) { s=6; base=E_SW1; }
  else if (e < E_SWO) { s=7; base=E_SB1; }
  else if (e < E_SBO) { s=8; base=E_SWO; }
  else                { s=9; base=E_SBO; }
  size_t off = e - base;
  unsigned short v;
  if (fp32) v = f2bf(((const float*)a.s[s])[off]);
  else      v = ((const unsigned short*)a.s[s])[off];
  dst[e] = v;
}

// ---------------- kA: gather + relu embeddings -> X (bf16) ----------------
__global__ __launch_bounds__(256) void kA(const void* __restrict__ emb_,
                                          const int* __restrict__ goal,
                                          unsigned short* __restrict__ X,
                                          const unsigned int* __restrict__ flag){
  int m = blockIdx.x;
  int t4 = threadIdx.x;
  if (t4 >= 192) return;      // 192 * 4 elems = 768
  ushort4 v;
  if (m > MROWS){
    v.x = 0; v.y = 0; v.z = 0; v.w = 0;               // zero padding rows
  } else {
    int tok, norelu;
    if (m < MROWS){ int t = m >> 6, b = m & 63; tok = goal[b*Lseq + t]; norelu = 0; }
    else          { tok = 1; norelu = 1; }            // end token id=1, NO relu
    if (*flag){
      const float* ef = (const float*)emb_;
      float4 f = ((const float4*)(ef + (size_t)tok*Hd))[t4];
      if (!norelu){
        f.x = fmaxf(f.x, 0.f); f.y = fmaxf(f.y, 0.f);
        f.z = fmaxf(f.z, 0.f); f.w = fmaxf(f.w, 0.f);
      }
      v.x = f2bf(f.x); v.y = f2bf(f.y); v.z = f2bf(f.z); v.w = f2bf(f.w);
    } else {
      const unsigned short* eu = (const unsigned short*)emb_;
      v = ((const ushort4*)(eu + (size_t)tok*Hd))[t4];
      if (!norelu){
        v.x = (v.x & 0x8000u) ? (unsigned short)0 : v.x;
        v.y = (v.y & 0x8000u) ? (unsigned short)0 : v.y;
        v.z = (v.z & 0x8000u) ? (unsigned short)0 : v.z;
        v.w = (v.w & 0x8000u) ? (unsigned short)0 : v.w;
      }
    }
  }
  ((ushort4*)(X + (size_t)m*Hd))[t4] = v;
}

// ---------------- kB: Gi = X @ W_ih^T + b_ih  (NT, bf16 MFMA) ----------------
__global__ __launch_bounds__(256) void kB(const unsigned short* __restrict__ X,
                                          const unsigned short* __restrict__ W,
                                          const unsigned short* __restrict__ bias,
                                          float* __restrict__ Gf,
                                          unsigned short* __restrict__ Gh,
                                          int gi_fp32){
  __shared__ __align__(16) unsigned short As[128*32];
  __shared__ __align__(16) unsigned short Bs[128*32];
  const int nblk = H3/128;  // 18
  int wg_m = blockIdx.x / nblk, wg_n = blockIdx.x % nblk;
  size_t m0 = (size_t)wg_m * 128; int n0 = wg_n * 128;
  int tid = threadIdx.x, wave = tid >> 6, lane = tid & 63;
  int wm = wave & 1, wn = wave >> 1;
  int quad = lane >> 4, mr = lane & 15;
  v4f acc[4][4];
  #pragma unroll
  for (int i=0;i<4;++i)
    #pragma unroll
    for(int j=0;j<4;++j){ acc[i][j][0]=0.f; acc[i][j][1]=0.f; acc[i][j][2]=0.f; acc[i][j][3]=0.f; }

  for (int kb = 0; kb < 24; ++kb){
    int koff = kb*64;  // bytes within a 1536B row
    #pragma unroll
    for (int i=0;i<2;++i){
      int inst = wave*2 + i;
      int c = inst*64 + lane;
      int row = c >> 2, k16 = (c & 3) * 16;
      const char* ga = (const char*)X + (m0 + row)*1536 + koff + k16;
      const char* gb = (const char*)W + ((size_t)(n0 + row))*1536 + koff + k16;
      __builtin_amdgcn_global_load_lds(
          (const __attribute__((address_space(1))) unsigned int*)ga,
          (__attribute__((address_space(3))) unsigned int*)(As + inst*512), 16, 0, 0);
      __builtin_amdgcn_global_load_lds(
          (const __attribute__((address_space(1))) unsigned int*)gb,
          (__attribute__((address_space(3))) unsigned int*)(Bs + inst*512), 16, 0, 0);
    }
    __syncthreads();
    short8 af[4], bfr[4];
    #pragma unroll
    for (int i=0;i<4;++i){
      af[i]  = *(const short8*)(As + (wm*64 + i*16 + mr)*32 + quad*8);
      bfr[i] = *(const short8*)(Bs + (wn*64 + i*16 + mr)*32 + quad*8);
    }
    #pragma unroll
    for (int i=0;i<4;++i)
      #pragma unroll
      for (int j=0;j<4;++j)
        acc[i][j] = __builtin_amdgcn_mfma_f32_16x16x32_bf16(af[i], bfr[j], acc[i][j], 0, 0, 0);
    __syncthreads();
  }
  // epilogue: + b_ih, store
  #pragma unroll
  for (int j=0;j<4;++j){
    int n = n0 + wn*64 + j*16 + mr;
    float bv = bf2f(bias[n]);
    #pragma unroll
    for (int i=0;i<4;++i){
      size_t mrow = m0 + wm*64 + i*16 + quad*4;
      #pragma unroll
      for (int r=0;r<4;++r){
        float val = acc[i][j][r] + bv;
        size_t off = (mrow + r)*H3 + n;
        if (gi_fp32) Gf[off] = val; else Gh[off] = f2bf(val);
      }
    }
  }
}

// ---------------- kC: persistent clustered GRU recurrence ----------------
// 8 clusters x 12 CUs. Each CU: 64 dims (x3 gates = 192 W_hh rows) register-resident
// as MFMA A-frags. Per-cluster device-scope barrier per step; Gi prefetched.
__global__ __launch_bounds__(256, 1) void kC(const unsigned short* __restrict__ whh,
    const unsigned short* __restrict__ bhh,
    const float* __restrict__ Gf, const unsigned short* __restrict__ Gh, int gi_fp32,
    unsigned short* __restrict__ hbuf,      // [NCLUST][2][16][768] bf16
    unsigned int* __restrict__ ctr,         // cluster c at ctr[c*64]
    float* __restrict__ finalT)             // [768][64] fp32
{
  __shared__ __align__(16) unsigned short hs[16*776];  // 16 rows x 1552B padded
  const int bid = blockIdx.x;
  const int cluster = bid / CUS_PER, cu = bid % CUS_PER;
  const int tid = threadIdx.x, wave = tid >> 6, lane = tid & 63;
  const int quad = lane >> 4, col = lane & 15;
  const int dim0 = cu*64 + wave*16;

  // preload W_hh A-frags: wf[g*24+kt], lane holds A[m=lane&15][k=quad*8+j]
  short8 wf[72];
  {
    const int mrow = lane & 15;
    #pragma unroll
    for (int g = 0; g < 3; ++g)
      #pragma unroll
      for (int kt = 0; kt < 24; ++kt){
        size_t row = (size_t)(g*Hd + dim0 + mrow);
        wf[g*24 + kt] = *(const short8*)(whh + row*Hd + kt*32 + quad*8);
      }
  }
  v4f biasv[3];
  #pragma unroll
  for (int g=0; g<3; ++g){
    ushort4 u = *(const ushort4*)(bhh + g*Hd + dim0 + quad*4);
    biasv[g][0]=bf2f(u.x); biasv[g][1]=bf2f(u.y); biasv[g][2]=bf2f(u.z); biasv[g][3]=bf2f(u.w);
  }
  v4f hold; hold[0]=0.f; hold[1]=0.f; hold[2]=0.f; hold[3]=0.f;
  unsigned int* myctr = ctr + cluster*64;
  unsigned short* hb = hbuf + (size_t)cluster * 2 * 12288;
  const int bgi = cluster*NB + (col < NB ? col : NB-1);
  const int bglob = cluster*NB + col;

  // prefetch gi for t=0
  v4f giv[3];
  {
    size_t ro = (size_t)bgi * H3;
    #pragma unroll
    for (int g=0; g<3; ++g){
      size_t off = ro + g*Hd + dim0 + quad*4;
      if (gi_fp32) giv[g] = *(const v4f*)(Gf + off);
      else { ushort4 u = *(const ushort4*)(Gh + off);
             giv[g][0]=bf2f(u.x); giv[g][1]=bf2f(u.y); giv[g][2]=bf2f(u.z); giv[g][3]=bf2f(u.w); }
    }
  }

  #pragma unroll 1
  for (int t = 0; t < 513; ++t){
    // wait: h_in for step t published (ctr >= 12*t)
    if (tid == 0){
      unsigned int target = (unsigned int)(CUS_PER * t);
      while (__hip_atomic_load(myctr, __ATOMIC_ACQUIRE, __HIP_MEMORY_SCOPE_AGENT) < target)
        __builtin_amdgcn_s_sleep(1);
    }
    __syncthreads();
    // copy h buf[t&1] (24576B) -> padded LDS
    {
      const uint4* src = (const uint4*)(hb + (size_t)(t & 1) * 12288);
      #pragma unroll
      for (int i = 0; i < 6; ++i){
        int c = i*256 + tid;
        int row = c / 96, k16 = c % 96;
        uint4 v = src[c];
        *(uint4*)(hs + row*776 + k16*8) = v;
      }
    }
    // prefetch gi for t+1 (hidden under MFMA+barrier)
    v4f gin[3];
    if (t < 512){
      size_t ro = (t+1 < 512) ? ((size_t)((t+1)*64 + bgi) * H3) : ((size_t)MROWS * H3);
      #pragma unroll
      for (int g=0; g<3; ++g){
        size_t off = ro + g*Hd + dim0 + quad*4;
        if (gi_fp32) gin[g] = *(const v4f*)(Gf + off);
        else { ushort4 u = *(const ushort4*)(Gh + off);
               gin[g][0]=bf2f(u.x); gin[g][1]=bf2f(u.y); gin[g][2]=bf2f(u.z); gin[g][3]=bf2f(u.w); }
      }
    }
    __syncthreads();
    // gh = W_hh @ h (+b_hh via acc init)
    v4f a0 = biasv[0], a1 = biasv[1], a2 = biasv[2];
    #pragma unroll
    for (int kt = 0; kt < 24; ++kt){
      short8 bfr = *(const short8*)(hs + col*776 + kt*32 + quad*8);
      a0 = __builtin_amdgcn_mfma_f32_16x16x32_bf16(wf[kt],      bfr, a0, 0,0,0);
      a1 = __builtin_amdgcn_mfma_f32_16x16x32_bf16(wf[24+kt],   bfr, a1, 0,0,0);
      a2 = __builtin_amdgcn_mfma_f32_16x16x32_bf16(wf[48+kt],   bfr, a2, 0,0,0);
    }
    // gates (fp32, pure per-lane: r/z/n share (lane,reg))
    v4f hnew;
    #pragma unroll
    for (int r=0; r<4; ++r){
      float rr = sigmoidf_(giv[0][r] + a0[r]);
      float zz = sigmoidf_(giv[1][r] + a1[r]);
      float nn = tanhf_(giv[2][r] + rr * a2[r]);
      hnew[r] = (1.f - zz)*nn + zz*hold[r];
    }
    if (t < 512){
      #pragma unroll
      for (int r=0;r<4;++r) hnew[r] = fmaxf(hnew[r], 0.f);   // relu'd steps
      if (col < NB){
        unsigned short* dst = hb + (size_t)(((t+1)&1))*12288 + (size_t)col*Hd + dim0 + quad*4;
        ushort4 pk; pk.x=f2bf(hnew[0]); pk.y=f2bf(hnew[1]); pk.z=f2bf(hnew[2]); pk.w=f2bf(hnew[3]);
        *(ushort4*)dst = pk;
      }
      hold = hnew;
      giv[0]=gin[0]; giv[1]=gin[1]; giv[2]=gin[2];
      __threadfence();
      __syncthreads();
      if (tid == 0)
        __hip_atomic_fetch_add(myctr, 1u, __ATOMIC_RELEASE, __HIP_MEMORY_SCOPE_AGENT);
    } else {
      // final gru step (end token): no relu, store fp32 transposed
      if (col < NB){
        #pragma unroll
        for (int r=0;r<4;++r)
          finalT[(size_t)(dim0 + quad*4 + r)*64 + bglob] = hnew[r];
      }
    }
  }
}

// ---------------- kD: scorer, fp32 K-split with atomics ----------------
__global__ __launch_bounds__(256) void kD(const float* __restrict__ finalT,
    const unsigned short* __restrict__ sw0, const unsigned short* __restrict__ sb0,
    const unsigned short* __restrict__ sw1, const unsigned short* __restrict__ sb1,
    const unsigned short* __restrict__ swo, const unsigned short* __restrict__ sbo,
    float* __restrict__ y0T, float* __restrict__ y1T,
    unsigned int* __restrict__ ctrD, void* __restrict__ outv,
    const unsigned int* __restrict__ flag)
{
  const int w = blockIdx.x;          // 0..191
  const int tid = threadIdx.x, wave = tid >> 6, lane = tid & 63;
  const int jg = w >> 2, kg = w & 3;
  const int j0 = jg*16 + wave*4;
  const int k0 = kg*192;
  // phase 1: y0T[j][b] partial = sum_k sw0[j][k]*finalT[k][b]
  {
    float acc[4] = {0.f,0.f,0.f,0.f};
    for (int k = k0; k < k0+192; ++k){
      float f = finalT[(size_t)k*64 + lane];
      #pragma unroll
      for (int jj=0; jj<4; ++jj)
        acc[jj] += bf2f(sw0[(size_t)(j0+jj)*Hd + k]) * f;
    }
    #pragma unroll
    for (int jj=0; jj<4; ++jj)
      atomicAdd(&y0T[(size_t)(j0+jj)*64 + lane], acc[jj]);
  }
  __threadfence(); __syncthreads();
  if (tid==0){
    __hip_atomic_fetch_add(ctrD, 1u, __ATOMIC_RELEASE, __HIP_MEMORY_SCOPE_AGENT);
    while (__hip_atomic_load(ctrD, __ATOMIC_ACQUIRE, __HIP_MEMORY_SCOPE_AGENT) < 192u)
      __builtin_amdgcn_s_sleep(1);
  }
  __syncthreads();
  // phase 2: y1T partial over relu(sb0+y0)
  {
    float acc[4] = {0.f,0.f,0.f,0.f};
    for (int k = k0; k < k0+192; ++k){
      float gv = fmaxf(bf2f(sb0[k]) + y0T[(size_t)k*64 + lane], 0.f);
      #pragma unroll
      for (int jj=0; jj<4; ++jj)
        acc[jj] += bf2f(sw1[(size_t)(j0+jj)*Hd + k]) * gv;
    }
    #pragma unroll
    for (int jj=0; jj<4; ++jj)
      atomicAdd(&y1T[(size_t)(j0+jj)*64 + lane], acc[jj]);
  }
  __threadfence(); __syncthreads();
  if (tid==0)
    __hip_atomic_fetch_add(ctrD, 1u, __ATOMIC_RELEASE, __HIP_MEMORY_SCOPE_AGENT);
  // phase 3: scores (WG 0, wave 0)
  if (w == 0){
    if (tid==0){
      while (__hip_atomic_load(ctrD, __ATOMIC_ACQUIRE, __HIP_MEMORY_SCOPE_AGENT) < 384u)
        __builtin_amdgcn_s_sleep(1);
    }
    __syncthreads();
    if (wave == 0){
      float acc = 0.f;
      for (int k = 0; k < Hd; ++k){
        float gv = fmaxf(bf2f(sb1[k]) + y1T[(size_t)k*64 + lane], 0.f);
        acc += bf2f(swo[k]) * gv;
      }
      float res = acc + bf2f(sbo[0]);
      if (*flag) ((float*)outv)[lane] = res;
      else       ((unsigned short*)outv)[lane] = f2bf(res);
    }
  }
}

extern "C" void kernel_launch(void* const* d_in, const int* in_sizes, int n_in,
                              void* d_out, int out_size, void* d_ws, size_t ws_size,
                              hipStream_t stream) {
  (void)in_sizes; (void)n_in; (void)out_size;
  const int* goal = (const int*)d_in[0];

  char* ws = (char*)d_ws;
  const size_t rest = SZ_H + SZ_FIN*3 + 4096;
  int gi_fp32 = (ws_size >= OFF_GI + SZ_GI_F + rest) ? 1 : 0;
  size_t gi_sz = gi_fp32 ? SZ_GI_F : SZ_GI_H;
  size_t OFF_H   = OFF_GI + gi_sz;
  size_t OFF_FIN = OFF_H + SZ_H;
  size_t OFF_Y0  = OFF_FIN + SZ_FIN;
  size_t OFF_Y1  = OFF_Y0 + SZ_FIN;
  size_t OFF_CTR = OFF_Y1 + SZ_FIN;

  unsigned short* X      = (unsigned short*)(ws);
  unsigned short* wsW    = (unsigned short*)(ws + OFF_W);
  float*          Gf     = (float*)(ws + OFF_GI);
  unsigned short* Gh     = (unsigned short*)(ws + OFF_GI);
  unsigned short* hbuf   = (unsigned short*)(ws + OFF_H);
  float*          finalT = (float*)(ws + OFF_FIN);
  float*          y0T    = (float*)(ws + OFF_Y0);
  float*          y1T    = (float*)(ws + OFF_Y1);
  unsigned int*   ctrC   = (unsigned int*)(ws + OFF_CTR);
  unsigned int*   ctrD   = (unsigned int*)(ws + OFF_CTR + 2048);
  unsigned int*   flag   = (unsigned int*)(ws + OFF_CTR + 3072);

  const unsigned short* wihC = wsW + E_WIH;
  const unsigned short* whhC = wsW + E_WHH;
  const unsigned short* bihC = wsW + E_BIH;
  const unsigned short* bhhC = wsW + E_BHH;
  const unsigned short* sw0C = wsW + E_SW0;
  const unsigned short* sb0C = wsW + E_SB0;
  const unsigned short* sw1C = wsW + E_SW1;
  const unsigned short* sb1C = wsW + E_SB1;
  const unsigned short* swoC = wsW + E_SWO;
  const unsigned short* sboC = wsW + E_SBO;

  size_t zbytes = (OFF_CTR + 4096) - OFF_H;
  kZ<<<256, 256, 0, stream>>>((uint4*)(ws + OFF_H), (int)(zbytes/16));
  kDet<<<1, 256, 0, stream>>>((const unsigned short*)d_in[1], flag);
  CvtArgs ca;
  for (int i = 0; i < 10; ++i) ca.s[i] = d_in[2 + i];
  kCvt<<<(int)((E_TOT + 255)/256), 256, 0, stream>>>(ca, wsW, flag);
  kA<<<MPAD, 256, 0, stream>>>(d_in[1], goal, X, flag);
  kB<<<257*18, 256, 0, stream>>>(X, wihC, bihC, Gf, Gh, gi_fp32);
  kC<<<NCLUST*CUS_PER, 256, 0, stream>>>(whhC, bhhC, Gf, Gh, gi_fp32, hbuf, ctrC, finalT);
  kD<<<192, 256, 0, stream>>>(finalT, sw0C, sb0C, sw1C, sb1C, swoC, sboC,
                              y0T, y1T, ctrD, d_out, flag);
}

// Round 3
// 2092.300 us; speedup vs baseline: 3.7490x; 3.7490x over previous
//
#include <hip/hip_runtime.h>
#include <stdint.h>

#define Hd 768
#define H3 2304
#define Bsz 64
#define Lseq 512
#define MROWS 32768           // L*B real rows
#define MPAD 32896            // 257*128
#define NB 8                  // batch per cluster
#define NCLUST 8
#define CUS_PER 12

// ---- workspace layout (bytes) ----
#define OFF_W   50528256UL          // after X (MPAD*768*2)
#define W_SZ    9451072UL
#define OFF_GI  (OFF_W + W_SZ)      // 59,979,328
#define SZ_GI_F 303169536UL
#define SZ_GI_H 151584768UL
#define SZ_H    393216UL            // tagged h: 8 clusters x 2 parity x 3072 x 8B
#define SZ_FIN  196608UL
// converted-region element offsets (ushort index from ws+OFF_W)
#define E_WIH 0UL
#define E_WHH 1769472UL
#define E_BIH 3538944UL
#define E_BHH 3541248UL
#define E_SW0 3543552UL
#define E_SB0 4133376UL
#define E_SW1 4134144UL
#define E_SB1 4723968UL
#define E_SWO 4724736UL
#define E_SBO 4725504UL
#define E_TOT 4725505UL

typedef float v4f __attribute__((ext_vector_type(4)));
typedef short short8 __attribute__((ext_vector_type(8)));

__device__ inline float bf2f(unsigned short u){
  union { unsigned int i; float f; } v; v.i = ((unsigned int)u) << 16; return v.f;
}
__device__ inline unsigned short f2bf(float f){
  union { float f; unsigned int i; } v; v.f = f;
  unsigned int x = v.i;
  return (unsigned short)((x + 0x7fffu + ((x >> 16) & 1u)) >> 16);
}
__device__ inline float sigmoidf_(float x){ return 1.f/(1.f + __expf(-x)); }
__device__ inline float tanhf_(float x){
  float a = fabsf(x);
  float e = __expf(-2.f*a);
  float t = (1.f - e)/(1.f + e);
  return copysignf(t, x);
}

// ---------------- kZ: zero control/accumulator region ----------------
__global__ void kZ(uint4* p, int n16){
  int idx = blockIdx.x*blockDim.x + threadIdx.x;
  uint4 z; z.x=0; z.y=0; z.z=0; z.w=0;
  for (int i = idx; i < n16; i += gridDim.x*blockDim.x) p[i] = z;
}

// ---------------- kDet: detect fp32 (1) vs bf16 (0) input encoding ----------
__global__ void kDet(const unsigned short* __restrict__ emb_u, unsigned int* flag){
  __shared__ int cnt;
  if (threadIdx.x == 0) cnt = 0;
  __syncthreads();
  int local = 0;
  for (int i = threadIdx.x; i < 4096; i += 256){
    unsigned short b = emb_u[2*i];          // low half if fp32-underneath
    int e = (b >> 7) & 0xFF;
    if (e >= 0x89) local++;                 // |bf16| >= 2^10 (or NaN/inf)
  }
  atomicAdd(&cnt, local);
  __syncthreads();
  if (threadIdx.x == 0) *flag = (cnt > 64) ? 1u : 0u;
}

// ---------------- kCvt: weights -> bf16 copies in ws ----------------
struct CvtArgs { const void* s[10]; };
__global__ __launch_bounds__(256) void kCvt(CvtArgs a, unsigned short* __restrict__ dst,
                                            const unsigned int* __restrict__ flag){
  size_t e = (size_t)blockIdx.x*256 + threadIdx.x;
  if (e >= E_TOT) return;
  int fp32 = (int)*flag;
  int s; size_t base;
  if      (e < E_WHH) { s=0; base=E_WIH; }
  else if (e < E_BIH) { s=1; base=E_WHH; }
  else if (e < E_BHH) { s=2; base=E_BIH; }
  else if (e < E_SW0) { s=3; base=E_BHH; }
  else if (e < E_SB0) { s=4; base=E_SW0; }
  else if (e < E_SW1) { s=5; base=E_SB0; }
  else if (e < E_SB1) { s=6; base=E_SW1; }
  else if (e < E_SWO) { s=7; base=E_SB1; }
  else if (e < E_SBO) { s=8; base=E_SWO; }
  else                { s=9; base=E_SBO; }
  size_t off = e - base;
  unsigned short v;
  if (fp32) v = f2bf(((const float*)a.s[s])[off]);
  else      v = ((const unsigned short*)a.s[s])[off];
  dst[e] = v;
}

// ---------------- kA: gather + relu embeddings -> X (bf16) ----------------
__global__ __launch_bounds__(256) void kA(const void* __restrict__ emb_,
                                          const int* __restrict__ goal,
                                          unsigned short* __restrict__ X,
                                          const unsigned int* __restrict__ flag){
  int m = blockIdx.x;
  int t4 = threadIdx.x;
  if (t4 >= 192) return;      // 192 * 4 elems = 768
  ushort4 v;
  if (m > MROWS){
    v.x = 0; v.y = 0; v.z = 0; v.w = 0;               // zero padding rows
  } else {
    int tok, norelu;
    if (m < MROWS){ int t = m >> 6, b = m & 63; tok = goal[b*Lseq + t]; norelu = 0; }
    else          { tok = 1; norelu = 1; }            // end token id=1, NO relu
    if (*flag){
      const float* ef = (const float*)emb_;
      float4 f = ((const float4*)(ef + (size_t)tok*Hd))[t4];
      if (!norelu){
        f.x = fmaxf(f.x, 0.f); f.y = fmaxf(f.y, 0.f);
        f.z = fmaxf(f.z, 0.f); f.w = fmaxf(f.w, 0.f);
      }
      v.x = f2bf(f.x); v.y = f2bf(f.y); v.z = f2bf(f.z); v.w = f2bf(f.w);
    } else {
      const unsigned short* eu = (const unsigned short*)emb_;
      v = ((const ushort4*)(eu + (size_t)tok*Hd))[t4];
      if (!norelu){
        v.x = (v.x & 0x8000u) ? (unsigned short)0 : v.x;
        v.y = (v.y & 0x8000u) ? (unsigned short)0 : v.y;
        v.z = (v.z & 0x8000u) ? (unsigned short)0 : v.z;
        v.w = (v.w & 0x8000u) ? (unsigned short)0 : v.w;
      }
    }
  }
  ((ushort4*)(X + (size_t)m*Hd))[t4] = v;
}

// ---------------- kB: Gi = X @ W_ih^T + b_ih  (NT, bf16 MFMA) ----------------
__global__ __launch_bounds__(256) void kB(const unsigned short* __restrict__ X,
                                          const unsigned short* __restrict__ W,
                                          const unsigned short* __restrict__ bias,
                                          float* __restrict__ Gf,
                                          unsigned short* __restrict__ Gh,
                                          int gi_fp32){
  __shared__ __align__(16) unsigned short As[128*32];
  __shared__ __align__(16) unsigned short Bs[128*32];
  const int nblk = H3/128;  // 18
  int wg_m = blockIdx.x / nblk, wg_n = blockIdx.x % nblk;
  size_t m0 = (size_t)wg_m * 128; int n0 = wg_n * 128;
  int tid = threadIdx.x, wave = tid >> 6, lane = tid & 63;
  int wm = wave & 1, wn = wave >> 1;
  int quad = lane >> 4, mr = lane & 15;
  v4f acc[4][4];
  #pragma unroll
  for (int i=0;i<4;++i)
    #pragma unroll
    for(int j=0;j<4;++j){ acc[i][j][0]=0.f; acc[i][j][1]=0.f; acc[i][j][2]=0.f; acc[i][j][3]=0.f; }

  for (int kb = 0; kb < 24; ++kb){
    int koff = kb*64;  // bytes within a 1536B row
    #pragma unroll
    for (int i=0;i<2;++i){
      int inst = wave*2 + i;
      int c = inst*64 + lane;
      int row = c >> 2, k16 = (c & 3) * 16;
      const char* ga = (const char*)X + (m0 + row)*1536 + koff + k16;
      const char* gb = (const char*)W + ((size_t)(n0 + row))*1536 + koff + k16;
      __builtin_amdgcn_global_load_lds(
          (const __attribute__((address_space(1))) unsigned int*)ga,
          (__attribute__((address_space(3))) unsigned int*)(As + inst*512), 16, 0, 0);
      __builtin_amdgcn_global_load_lds(
          (const __attribute__((address_space(1))) unsigned int*)gb,
          (__attribute__((address_space(3))) unsigned int*)(Bs + inst*512), 16, 0, 0);
    }
    __syncthreads();
    short8 af[4], bfr[4];
    #pragma unroll
    for (int i=0;i<4;++i){
      af[i]  = *(const short8*)(As + (wm*64 + i*16 + mr)*32 + quad*8);
      bfr[i] = *(const short8*)(Bs + (wn*64 + i*16 + mr)*32 + quad*8);
    }
    #pragma unroll
    for (int i=0;i<4;++i)
      #pragma unroll
      for (int j=0;j<4;++j)
        acc[i][j] = __builtin_amdgcn_mfma_f32_16x16x32_bf16(af[i], bfr[j], acc[i][j], 0, 0, 0);
    __syncthreads();
  }
  // epilogue: + b_ih, store
  #pragma unroll
  for (int j=0;j<4;++j){
    int n = n0 + wn*64 + j*16 + mr;
    float bv = bf2f(bias[n]);
    #pragma unroll
    for (int i=0;i<4;++i){
      size_t mrow = m0 + wm*64 + i*16 + quad*4;
      #pragma unroll
      for (int r=0;r<4;++r){
        float val = acc[i][j][r] + bv;
        size_t off = (mrow + r)*H3 + n;
        if (gi_fp32) Gf[off] = val; else Gh[off] = f2bf(val);
      }
    }
  }
}

// ---------------- kC: persistent clustered GRU recurrence ----------------
// Fence-free: h exchanged as (tag<<32 | 2xbf16) 8B words via relaxed agent-scope
// atomics (sc0 sc1 -> coherent point, NO buffer_wbl2/buffer_inv). The tag poll
// IS the cluster barrier; double-buffer by parity. kZ zeroing = tag0 = h0=0.
__global__ __launch_bounds__(256, 1) void kC(const unsigned short* __restrict__ whh,
    const unsigned short* __restrict__ bhh,
    const float* __restrict__ Gf, const unsigned short* __restrict__ Gh, int gi_fp32,
    unsigned long long* __restrict__ tbuf,  // [NCLUST][2][3072] tagged words
    float* __restrict__ finalT)             // [768][64] fp32
{
  __shared__ __align__(16) unsigned short hs[16*776];  // 16 rows x 1552B padded
  const int bid = blockIdx.x;
  const int cluster = bid / CUS_PER, cu = bid % CUS_PER;
  const int tid = threadIdx.x, wave = tid >> 6, lane = tid & 63;
  const int quad = lane >> 4, col = lane & 15;
  const int dim0 = cu*64 + wave*16;

  // zero hs once (rows 8..15 are never written by unpack; keep them 0)
  for (int i = tid; i < 6208; i += 256) ((unsigned int*)hs)[i] = 0u;

  // preload W_hh A-frags: wf[g*24+kt], lane holds A[m=lane&15][k=quad*8+j]
  short8 wf[72];
  {
    const int mrow = lane & 15;
    #pragma unroll
    for (int g = 0; g < 3; ++g)
      #pragma unroll
      for (int kt = 0; kt < 24; ++kt){
        size_t row = (size_t)(g*Hd + dim0 + mrow);
        wf[g*24 + kt] = *(const short8*)(whh + row*Hd + kt*32 + quad*8);
      }
  }
  v4f biasv[3];
  #pragma unroll
  for (int g=0; g<3; ++g){
    ushort4 u = *(const ushort4*)(bhh + g*Hd + dim0 + quad*4);
    biasv[g][0]=bf2f(u.x); biasv[g][1]=bf2f(u.y); biasv[g][2]=bf2f(u.z); biasv[g][3]=bf2f(u.w);
  }
  v4f hold; hold[0]=0.f; hold[1]=0.f; hold[2]=0.f; hold[3]=0.f;
  unsigned long long* tb0 = tbuf + (size_t)cluster * 6144;
  const int bgi = cluster*NB + (col < NB ? col : NB-1);
  const int bglob = cluster*NB + col;
  const int wpair = cu*32 + wave*8 + quad*2;   // writer uint2 pair base within batch row

  // prefetch gi for t=0
  v4f giv[3];
  {
    size_t ro = (size_t)bgi * H3;
    #pragma unroll
    for (int g=0; g<3; ++g){
      size_t off = ro + g*Hd + dim0 + quad*4;
      if (gi_fp32) giv[g] = *(const v4f*)(Gf + off);
      else { ushort4 u = *(const ushort4*)(Gh + off);
             giv[g][0]=bf2f(u.x); giv[g][1]=bf2f(u.y); giv[g][2]=bf2f(u.z); giv[g][3]=bf2f(u.w); }
    }
  }
  __syncthreads();   // hs zero-init done before first unpack

  #pragma unroll 1
  for (int t = 0; t < 513; ++t){
    // prefetch gi for t+1 first (independent of h)
    v4f gin[3];
    if (t < 512){
      size_t ro = (t+1 < 512) ? ((size_t)((t+1)*64 + bgi) * H3) : ((size_t)MROWS * H3);
      #pragma unroll
      for (int g=0; g<3; ++g){
        size_t off = ro + g*Hd + dim0 + quad*4;
        if (gi_fp32) gin[g] = *(const v4f*)(Gf + off);
        else { ushort4 u = *(const ushort4*)(Gh + off);
               gin[g][0]=bf2f(u.x); gin[g][1]=bf2f(u.y); gin[g][2]=bf2f(u.z); gin[g][3]=bf2f(u.w); }
      }
    }
    // poll tagged h-words for step t (wave polls its quarter; poll == barrier)
    unsigned long long vals[12];
    {
      unsigned long long* tb = tb0 + (size_t)(t & 1) * 3072;
      const unsigned int tagw = (unsigned int)t;
      const int base = wave*768 + lane;
      for (;;){
        #pragma unroll
        for (int j = 0; j < 12; ++j)
          vals[j] = __hip_atomic_load(tb + base + j*64, __ATOMIC_RELAXED, __HIP_MEMORY_SCOPE_AGENT);
        int ok = 1;
        #pragma unroll
        for (int j = 0; j < 12; ++j) ok &= ((unsigned int)(vals[j] >> 32) == tagw);
        if (__all(ok)) break;
      }
    }
    // unpack payloads into padded LDS (wave's slice = batches 2w,2w+1, all dims)
    #pragma unroll
    for (int j = 0; j < 12; ++j){
      int s = j*64 + lane;
      int hi = (s >= 384) ? 1 : 0;
      int b = wave*2 + hi;
      int p = s - hi*384;
      *(unsigned int*)(hs + b*776 + 2*p) = (unsigned int)vals[j];
    }
    __syncthreads();
    // gh = W_hh @ h (+b_hh via acc init)
    v4f a0 = biasv[0], a1 = biasv[1], a2 = biasv[2];
    #pragma unroll
    for (int kt = 0; kt < 24; ++kt){
      short8 bfr = *(const short8*)(hs + col*776 + kt*32 + quad*8);
      a0 = __builtin_amdgcn_mfma_f32_16x16x32_bf16(wf[kt],      bfr, a0, 0,0,0);
      a1 = __builtin_amdgcn_mfma_f32_16x16x32_bf16(wf[24+kt],   bfr, a1, 0,0,0);
      a2 = __builtin_amdgcn_mfma_f32_16x16x32_bf16(wf[48+kt],   bfr, a2, 0,0,0);
    }
    // gates (fp32, pure per-lane: r/z/n share (lane,reg))
    v4f hnew;
    #pragma unroll
    for (int r=0; r<4; ++r){
      float rr = sigmoidf_(giv[0][r] + a0[r]);
      float zz = sigmoidf_(giv[1][r] + a1[r]);
      float nn = tanhf_(giv[2][r] + rr * a2[r]);
      hnew[r] = (1.f - zz)*nn + zz*hold[r];
    }
    if (t < 512){
      #pragma unroll
      for (int r=0;r<4;++r) hnew[r] = fmaxf(hnew[r], 0.f);   // relu'd steps
      if (col < NB){
        unsigned long long* dst = tb0 + (size_t)((t+1) & 1) * 3072 + col*384 + wpair;
        unsigned int p0 = (unsigned int)f2bf(hnew[0]) | ((unsigned int)f2bf(hnew[1]) << 16);
        unsigned int p1 = (unsigned int)f2bf(hnew[2]) | ((unsigned int)f2bf(hnew[3]) << 16);
        unsigned long long tg = ((unsigned long long)(unsigned int)(t+1)) << 32;
        __hip_atomic_store(dst,     tg | p0, __ATOMIC_RELAXED, __HIP_MEMORY_SCOPE_AGENT);
        __hip_atomic_store(dst + 1, tg | p1, __ATOMIC_RELAXED, __HIP_MEMORY_SCOPE_AGENT);
      }
      hold = hnew;
      giv[0]=gin[0]; giv[1]=gin[1]; giv[2]=gin[2];
    } else {
      // final gru step (end token): no relu, store fp32 transposed
      if (col < NB){
        #pragma unroll
        for (int r=0;r<4;++r)
          finalT[(size_t)(dim0 + quad*4 + r)*64 + bglob] = hnew[r];
      }
    }
  }
}

// ---------------- scorer: 3 stream-ordered kernels (no device barriers) -----
__global__ __launch_bounds__(256) void kD1(const float* __restrict__ finalT,
    const unsigned short* __restrict__ sw0, float* __restrict__ y0T){
  const int w = blockIdx.x;          // 0..191
  const int tid = threadIdx.x, wave = tid >> 6, lane = tid & 63;
  const int j0 = (w >> 2)*16 + wave*4;
  const int k0 = (w & 3)*192;
  float acc[4] = {0.f,0.f,0.f,0.f};
  for (int k = k0; k < k0+192; ++k){
    float f = finalT[(size_t)k*64 + lane];
    #pragma unroll
    for (int jj=0; jj<4; ++jj)
      acc[jj] += bf2f(sw0[(size_t)(j0+jj)*Hd + k]) * f;
  }
  #pragma unroll
  for (int jj=0; jj<4; ++jj)
    atomicAdd(&y0T[(size_t)(j0+jj)*64 + lane], acc[jj]);
}

__global__ __launch_bounds__(256) void kD2(const float* __restrict__ y0T,
    const unsigned short* __restrict__ sb0, const unsigned short* __restrict__ sw1,
    float* __restrict__ y1T){
  const int w = blockIdx.x;
  const int tid = threadIdx.x, wave = tid >> 6, lane = tid & 63;
  const int j0 = (w >> 2)*16 + wave*4;
  const int k0 = (w & 3)*192;
  float acc[4] = {0.f,0.f,0.f,0.f};
  for (int k = k0; k < k0+192; ++k){
    float gv = fmaxf(bf2f(sb0[k]) + y0T[(size_t)k*64 + lane], 0.f);
    #pragma unroll
    for (int jj=0; jj<4; ++jj)
      acc[jj] += bf2f(sw1[(size_t)(j0+jj)*Hd + k]) * gv;
  }
  #pragma unroll
  for (int jj=0; jj<4; ++jj)
    atomicAdd(&y1T[(size_t)(j0+jj)*64 + lane], acc[jj]);
}

__global__ void kD3(const float* __restrict__ y1T,
    const unsigned short* __restrict__ sb1, const unsigned short* __restrict__ swo,
    const unsigned short* __restrict__ sbo, void* __restrict__ outv,
    const unsigned int* __restrict__ flag){
  const int lane = threadIdx.x;   // 64 threads = 64 batches
  float acc = 0.f;
  for (int k = 0; k < Hd; ++k){
    float gv = fmaxf(bf2f(sb1[k]) + y1T[(size_t)k*64 + lane], 0.f);
    acc += bf2f(swo[k]) * gv;
  }
  float res = acc + bf2f(sbo[0]);
  if (*flag) ((float*)outv)[lane] = res;
  else       ((unsigned short*)outv)[lane] = f2bf(res);
}

extern "C" void kernel_launch(void* const* d_in, const int* in_sizes, int n_in,
                              void* d_out, int out_size, void* d_ws, size_t ws_size,
                              hipStream_t stream) {
  (void)in_sizes; (void)n_in; (void)out_size;
  const int* goal = (const int*)d_in[0];

  char* ws = (char*)d_ws;
  const size_t rest = SZ_H + SZ_FIN*3 + 4096;
  int gi_fp32 = (ws_size >= OFF_GI + SZ_GI_F + rest) ? 1 : 0;
  size_t gi_sz = gi_fp32 ? SZ_GI_F : SZ_GI_H;
  size_t OFF_H   = OFF_GI + gi_sz;
  size_t OFF_FIN = OFF_H + SZ_H;
  size_t OFF_Y0  = OFF_FIN + SZ_FIN;
  size_t OFF_Y1  = OFF_Y0 + SZ_FIN;
  size_t OFF_CTR = OFF_Y1 + SZ_FIN;

  unsigned short* X      = (unsigned short*)(ws);
  unsigned short* wsW    = (unsigned short*)(ws + OFF_W);
  float*          Gf     = (float*)(ws + OFF_GI);
  unsigned short* Gh     = (unsigned short*)(ws + OFF_GI);
  unsigned long long* tbuf = (unsigned long long*)(ws + OFF_H);
  float*          finalT = (float*)(ws + OFF_FIN);
  float*          y0T    = (float*)(ws + OFF_Y0);
  float*          y1T    = (float*)(ws + OFF_Y1);
  unsigned int*   flag   = (unsigned int*)(ws + OFF_CTR + 3072);

  const unsigned short* wihC = wsW + E_WIH;
  const unsigned short* whhC = wsW + E_WHH;
  const unsigned short* bihC = wsW + E_BIH;
  const unsigned short* bhhC = wsW + E_BHH;
  const unsigned short* sw0C = wsW + E_SW0;
  const unsigned short* sb0C = wsW + E_SB0;
  const unsigned short* sw1C = wsW + E_SW1;
  const unsigned short* sb1C = wsW + E_SB1;
  const unsigned short* swoC = wsW + E_SWO;
  const unsigned short* sboC = wsW + E_SBO;

  size_t zbytes = (OFF_CTR + 4096) - OFF_H;
  kZ<<<256, 256, 0, stream>>>((uint4*)(ws + OFF_H), (int)(zbytes/16));
  kDet<<<1, 256, 0, stream>>>((const unsigned short*)d_in[1], flag);
  CvtArgs ca;
  for (int i = 0; i < 10; ++i) ca.s[i] = d_in[2 + i];
  kCvt<<<(int)((E_TOT + 255)/256), 256, 0, stream>>>(ca, wsW, flag);
  kA<<<MPAD, 256, 0, stream>>>(d_in[1], goal, X, flag);
  kB<<<257*18, 256, 0, stream>>>(X, wihC, bihC, Gf, Gh, gi_fp32);
  kC<<<NCLUST*CUS_PER, 256, 0, stream>>>(whhC, bhhC, Gf, Gh, gi_fp32, tbuf, finalT);
  kD1<<<192, 256, 0, stream>>>(finalT, sw0C, y0T);
  kD2<<<192, 256, 0, stream>>>(y0T, sb0C, sw1C, y1T);
  kD3<<<1, 64, 0, stream>>>(y1T, sb1C, swoC, sboC, d_out, flag);
}